// Round 2
// baseline (1853.107 us; speedup 1.0000x reference)
//
#include <hip/hip_runtime.h>

// dictloss: ss_b = D@X + meanY; overlap-add over stride-1 patches; masked blend; A@v; MSE.
// Key identity: patches[p,k]=k+p  =>  ss_p_sum[n] = sum_a sum_p d[p,a]*x[a,n-p]  (FIR bank)
// plus meanY*npp[n] (npp given as input).
//
// R5 changes vs R3/R4 (921.6us total; profile showed all 4 kernels <328us each, harness
// poison fills ~333us dominate the top-5; conv modeled at 2.5-5x its 58us VALU floor,
// theory = TLP-stall-bound at 4 blocks/CU with grid exactly 4/CU):
//  - conv: single LDS x-buffer + T14 reg-staged prefetch (global->VGPR during compute,
//    ds_write after read-barrier, next loads issued after write-barrier so the barrier's
//    vmcnt(0) drain never exposes an in-flight load). LDS 39.9KB -> 19.9KB/block.
//  - NSPLIT 16->32 (APS=8): grid 2048 blocks so >4 blocks/CU exist; occupancy capacity
//    LDS=8, VGPR~6 blocks/CU -> ~24 waves/CU (1.5x TLP). x traffic unchanged.
//  - same swizzled LDS layout (physical slot swz(q) holds logical q; swz self-inverse,
//    2 lanes/bank-group per 16-lane phase = conflict-free per m136).

namespace {
constexpr int kP = 64;        // patch size
constexpr int kA = 256;       // atoms
constexpr int kN = 262144;    // signal length
constexpr int kK = 262081;    // npatches
constexpr int kM = 512;       // rows of A

constexpr int CB = 256;             // threads per conv block
constexpr int OPT = 16;             // outputs per thread
constexpr int NB = CB * OPT;        // 4096 outputs per block
constexpr int NCHUNK = kN / NB;     // 64
constexpr int NSPLIT = 32;          // atom splits (partial buffers)
constexpr int APS = kA / NSPLIT;    // 8 atoms per block
constexpr int XS4 = 1088;           // float4 slots in x buffer (1044 staged + pad)
constexpr int DPF = 80;             // floats per padded/reversed coefficient row
constexpr int GV_CH = 8;            // gemv column chunks per row

__device__ __forceinline__ int swz(int l4) { return l4 ^ ((l4 >> 3) & 7); }

__device__ __forceinline__ float f4c(const float4& v, int i) {
  switch (i & 3) {
    case 0: return v.x;
    case 1: return v.y;
    case 2: return v.z;
    default: return v.w;
  }
}

// Load atom a's x slice [k0 .. k0+4175], k0 = n0-63-SA (16B-aligned since kK%4==1),
// into registers: 4 float4/thread (logical slots q*256+tid) + tail (slots 1024..1043,
// tid<20). OOB clamped; edge blocks overwrite those slots with zeros before compute.
__device__ __forceinline__ void load_regs(const float* __restrict__ x, int a, int n0,
                                          int tid, float4 r[4], float4& rt) {
  const int SA = (a + 1) & 3;
  const int g4base = (a * kK + n0 - 63 - SA) >> 2;
  const int g4max = (kA / 4) * kK - 1;
  const float4* __restrict__ x4 = (const float4*)x;
#pragma unroll
  for (int q = 0; q < 4; ++q) {
    int g4 = g4base + q * 256 + tid;               // coalesced: lane-consecutive
    g4 = g4 < 0 ? 0 : (g4 > g4max ? g4max : g4);
    r[q] = x4[g4];
  }
  if (tid < 20) {
    int g4 = g4base + 1024 + tid;
    g4 = g4 < 0 ? 0 : (g4 > g4max ? g4max : g4);
    rt = x4[g4];
  }
}

// Write staged regs to LDS at swizzled physical slots (permutation within 64-groups:
// 2 lanes/bank-group per phase = conflict-free).
__device__ __forceinline__ void write_lds(float4* xs, int tid, const float4 r[4],
                                          const float4& rt) {
#pragma unroll
  for (int q = 0; q < 4; ++q) {
    const int l = q * 256 + tid;
    xs[(l & ~63) | swz(l & 63)] = r[q];
  }
  if (tid < 20) xs[1024 + swz(tid)] = rt;
}

// acc[j] += sum_{q'=0..67} dp[q'] * xs[16t + j + q'], dp pre-reversed & zero-padded.
__device__ __forceinline__ void compute_atom(const float4* __restrict__ xs4,
                                             const float* __restrict__ dpf,
                                             int al, float* __restrict__ acc) {
  const int t4 = (int)threadIdx.x * 4;
  const float4* __restrict__ dp4 = (const float4*)(dpf + al * DPF);
  float4 w[5];
#pragma unroll
  for (int q = 0; q < 4; ++q) w[q] = xs4[swz(t4 + q)];
#pragma unroll
  for (int c = 0; c < 17; ++c) {
    w[(c + 4) % 5] = xs4[swz(t4 + c + 4)];
    float4 D = dp4[c];
#pragma unroll
    for (int i = 0; i < 4; ++i) {
      float coef = f4c(D, i);
#pragma unroll
      for (int j = 0; j < OPT; ++j) {
        int off = i + j;                           // 0..18
        acc[j] = fmaf(coef, f4c(w[(c + (off >> 2)) % 5], off & 3), acc[j]);
      }
    }
  }
}

__global__ __launch_bounds__(CB, 6) void conv_kernel(const float* __restrict__ d,
                                                     const float* __restrict__ x,
                                                     float* __restrict__ part) {
  __shared__ float4 xs[XS4];
  __shared__ float dpf[APS * DPF];
  const int n0 = blockIdx.x * NB;
  const int a0 = blockIdx.y * APS;
  const int tid = threadIdx.x;

  // Build padded+reversed coefficient table: dp[al][q'] = d[63+SA-q'][a0+al] for
  // q' in [SA, SA+63], else 0.  out[n] = sum_q' dp[q']*x[k0+16t+j+q'].
  for (int idx = tid; idx < APS * DPF; idx += CB) {
    int al = idx / DPF, q = idx - al * DPF;
    int a = a0 + al, SA = (a + 1) & 3;
    float v = 0.0f;
    if (q >= SA && q < SA + 64) v = d[(63 + SA - q) * kA + a];
    dpf[idx] = v;
  }

  float4 r[4];
  float4 rt = make_float4(0.f, 0.f, 0.f, 0.f);
  load_regs(x, a0, n0, tid, r, rt);                // atom 0
  write_lds(xs, tid, r, rt);                       // vmcnt waited via reg deps
  __syncthreads();                                 // xs(atom0) + dpf visible
  load_regs(x, a0 + 1, n0, tid, r, rt);            // prefetch atom 1 (APS >= 2)

  float acc[OPT];
#pragma unroll
  for (int j = 0; j < OPT; ++j) acc[j] = 0.0f;

  const bool first = (blockIdx.x == 0);
  const bool last = (blockIdx.x == NCHUNK - 1);

#pragma unroll 1
  for (int al = 0; al < APS; ++al) {
    const int a = a0 + al;
    if (first | last) {                            // block-uniform; 2/64 of n-chunks
      const int SA = (a + 1) & 3;
      float* xsf = (float*)xs;
      if (first) {
        if (tid < 63 + SA) {                       // zero k<0 halo (floats 0..62+SA)
          int slot = swz(tid >> 2);
          xsf[slot * 4 + (tid & 3)] = 0.0f;
        }
      } else {
        const int iK = kK - n0 + 63 + SA;          // zero k>=kK tail
        for (int i = iK + tid; i < 4176; i += CB) {
          int slot = swz(i >> 2);
          xsf[slot * 4 + (i & 3)] = 0.0f;
        }
      }
      __syncthreads();
    }
    compute_atom(xs, dpf, al, acc);
    if (al + 1 < APS) {
      __syncthreads();                             // all waves done reading xs
      write_lds(xs, tid, r, rt);                   // atom al+1 (loads landed: full
      __syncthreads();                             //   compute window in flight)
      if (al + 2 < APS) load_regs(x, a0 + al + 2, n0, tid, r, rt);  // after barrier:
    }                                              //   never drained by syncthreads
  }

  float4* outp = (float4*)(part + (size_t)blockIdx.y * kN + n0 + tid * OPT);
#pragma unroll
  for (int j = 0; j < 4; ++j)
    outp[j] = make_float4(acc[4 * j], acc[4 * j + 1], acc[4 * j + 2], acc[4 * j + 3]);
}

__global__ void vmask_kernel(const float* __restrict__ part, const float* __restrict__ ds,
                             const float* __restrict__ npp, const float* __restrict__ vb,
                             const float* __restrict__ sRef,
                             const float* __restrict__ pMeanY,
                             const float* __restrict__ pLam2, float* __restrict__ v) {
  const int i = blockIdx.x * blockDim.x + threadIdx.x;   // float4 index over kN/4
  const float meanY = pMeanY[0];
  const float lam2 = pLam2[0];
  float4 s = make_float4(0.f, 0.f, 0.f, 0.f);
#pragma unroll
  for (int c = 0; c < NSPLIT; ++c) {
    float4 p = ((const float4*)(part + (size_t)c * kN))[i];
    s.x += p.x; s.y += p.y; s.z += p.z; s.w += p.w;
  }
  const float4 dd = ((const float4*)ds)[i];
  const float4 np = ((const float4*)npp)[i];
  const float4 vbv = ((const float4*)vb)[i];
  const float4 sr = ((const float4*)sRef)[i];
  float4 r;
  r.x = (lam2 * dd.x + s.x + meanY * np.x) / (lam2 + np.x) * vbv.x + sr.x;
  r.y = (lam2 * dd.y + s.y + meanY * np.y) / (lam2 + np.y) * vbv.y + sr.y;
  r.z = (lam2 * dd.z + s.z + meanY * np.z) / (lam2 + np.z) * vbv.z + sr.z;
  r.w = (lam2 * dd.w + s.w + meanY * np.w) / (lam2 + np.w) * vbv.w + sr.w;
  ((float4*)v)[i] = r;
}

__global__ __launch_bounds__(256) void gemv_kernel(const float* __restrict__ A,
                                                   const float* __restrict__ v,
                                                   float* __restrict__ Tp) {
  const int m = blockIdx.x >> 3;                   // GV_CH == 8
  const int ch = blockIdx.x & (GV_CH - 1);
  const float4* __restrict__ A4 = (const float4*)(A + (size_t)m * kN);
  const float4* __restrict__ v4 = (const float4*)v;
  const int b0 = ch * (kN / 4 / GV_CH) + threadIdx.x;
  float s = 0.0f;
#pragma unroll 8
  for (int r = 0; r < 32; ++r) {
    float4 av = A4[b0 + r * 256];
    float4 vv = v4[b0 + r * 256];
    s = fmaf(av.x, vv.x, s);
    s = fmaf(av.y, vv.y, s);
    s = fmaf(av.z, vv.z, s);
    s = fmaf(av.w, vv.w, s);
  }
#pragma unroll
  for (int o = 32; o > 0; o >>= 1) s += __shfl_down(s, o, 64);
  __shared__ float red[4];
  if ((threadIdx.x & 63) == 0) red[threadIdx.x >> 6] = s;
  __syncthreads();
  if (threadIdx.x == 0) Tp[blockIdx.x] = red[0] + red[1] + red[2] + red[3];
}

__global__ void loss_kernel(const float* __restrict__ Tp, const float* __restrict__ Tarr,
                            float* __restrict__ out) {
  const int tid = threadIdx.x;
  float s = 0.0f;
  for (int m = tid; m < kM; m += 256) {
    float t = 0.0f;
#pragma unroll
    for (int c = 0; c < GV_CH; ++c) t += Tp[m * GV_CH + c];
    float df = t - Tarr[m];
    s = fmaf(df, df, s);
  }
#pragma unroll
  for (int o = 32; o > 0; o >>= 1) s += __shfl_down(s, o, 64);
  __shared__ float red[4];
  if ((tid & 63) == 0) red[tid >> 6] = s;
  __syncthreads();
  if (tid == 0) out[0] = (red[0] + red[1] + red[2] + red[3]) * (1.0f / kM);
}

}  // namespace

extern "C" void kernel_launch(void* const* d_in, const int* in_sizes, int n_in,
                              void* d_out, int out_size, void* d_ws, size_t ws_size,
                              hipStream_t stream) {
  const float* d    = (const float*)d_in[0];   // [1,64,256]
  const float* x    = (const float*)d_in[1];   // [256, 262081]
  const float* vb   = (const float*)d_in[3];   // [N,1]
  const float* npp  = (const float*)d_in[5];   // [N,1]
  const float* sRef = (const float*)d_in[6];   // [N,1]
  const float* A    = (const float*)d_in[7];   // [512, N]
  const float* Tarr = (const float*)d_in[8];   // [512,1]
  const float* pMeanY = (const float*)d_in[9];
  const float* ds   = (const float*)d_in[10];
  const float* pLam2 = (const float*)d_in[11];
  float* out = (float*)d_out;

  // workspace layout (floats): part[NSPLIT*kN] | v[kN] | Tp[kM*GV_CH]  (~34.6 MB)
  float* part = (float*)d_ws;
  float* v    = part + (size_t)NSPLIT * kN;
  float* Tp   = v + kN;

  conv_kernel<<<dim3(NCHUNK, NSPLIT), CB, 0, stream>>>(d, x, part);
  vmask_kernel<<<kN / 4 / 256, 256, 0, stream>>>(part, ds, npp, vb, sRef, pMeanY, pLam2, v);
  gemv_kernel<<<kM * GV_CH, 256, 0, stream>>>(A, v, Tp);
  loss_kernel<<<1, 256, 0, stream>>>(Tp, Tarr, out);
}